// Round 12
// baseline (462.927 us; speedup 1.0000x reference)
//
#include <hip/hip_runtime.h>

// ---------------- problem constants ----------------
#define NN    8192
#define KK    32
#define DD    64
#define DID   32
#define HD    256
#define BS    4
#define TT    8
#define DSCAN 1024
#define TN    16     // nodes per block
#define ROWS  64     // TN*BS MFMA rows; row r = i*4 + b
#define XSTR  264    // LDS row stride in f16

typedef _Float16 f16;
typedef f16   f16x4 __attribute__((ext_vector_type(4)));
typedef f16   f16x8 __attribute__((ext_vector_type(8)));
typedef float f32x4 __attribute__((ext_vector_type(4)));

// ---------------- device-global workspace (float units) ----------------
#define OFF_H      0u          // BS*NN*DD f32 = 2097152
#define OFF_WCONN  2097152u    // BS*NN*KK f32 = 1048576
#define OFF_IDENT  3145728u    // NN*DID f32 = 262144 (updated in place)
#define OFF_MSGS   3407872u    // two buffers: NN*BS*DD f16 = 1048576 float slots EACH -> [3407872, 5505024)
#define OFF_HEBB16 5505024u    // BS*NN*KK f16 = 524288 float slots
#define MSG_ELEMS  (NN * BS * DD)   // f16 elems per buffer (2097152)
#define WS_TOTAL   6029312u

__device__ float g_ws[WS_TOTAL];

// ---------------- pre-swizzled f16 weights (MFMA B-frag order, K-blocks permuted) ----
#define OFF16_DW1  0u        // 16*8*512
#define OFF16_DW2  65536u    // 5*8*512 (65 cols padded to 80)
#define OFF16_SW1  86016u    // 16*7*512
#define OFF16_SW2  143360u   // 4*8*512
#define OFF16_MW1  159744u   // 16*3*512
#define OFF16_MW2  184320u   // 4*8*512
#define W16_TOTAL  200704u

__device__ f16 g_wf16[W16_TOTAL];

// init work-item partition
#define N_COPY4  851968u     // (2097152+1048576+262144)/4
#define N_MSG4   524288u     // NN*BS*DD/4 (f16x4 groups)
#define N_W16    200704u
#define N_HB4    262144u     // BS*NN*KK/4 (f16x4 groups)
#define N_INIT_TOTAL (N_COPY4 + N_MSG4 + N_W16 + N_HB4)

// ---------------- numeric helpers ----------------
__device__ __forceinline__ float fast_sigmoid(float x) { return 1.f / (1.f + __expf(-x)); }
__device__ __forceinline__ float fast_silu(float x)    { return x / (1.f + __expf(-x)); }
__device__ __forceinline__ float fast_tanh(float x) {
    float ax = fabsf(x);
    float t  = __expf(-2.f * ax);
    float r  = (1.f - t) / (1.f + t);
    return copysignf(r, x);
}
__device__ __forceinline__ f16x4 cvt4(float4 v) {
    f16x4 o; o[0] = (f16)v.x; o[1] = (f16)v.y; o[2] = (f16)v.z; o[3] = (f16)v.w; return o;
}

// ---------------- merged init kernel ----------------
struct Seg { const float* src; unsigned int dst_off; unsigned int len4; };
struct WL { const float* W; int Nsrc; int KB; unsigned int dst; int sz; int perm[8]; };
struct AllArgs { Seg seg[3]; const float* m0; WL l[6]; const float* hebbf; };

__global__ void init_all(AllArgs a) {
    unsigned int i = blockIdx.x * 256 + threadIdx.x;
    if (i < N_COPY4) {
#pragma unroll
        for (int s = 0; s < 3; ++s) {
            unsigned int L = a.seg[s].len4;
            if (i < L) {
                const float4 v = ((const float4*)a.seg[s].src)[i];
                *(float4*)&g_ws[a.seg[s].dst_off + 4u * i] = v;
                return;
            }
            i -= L;
        }
        return;
    }
    i -= N_COPY4;
    if (i < N_MSG4) {    // msgs: [b][n][d] f32 -> [n][b][d] f16 (buffer 0)
        const int n  = i >> 6;
        const int b  = (i >> 4) & 3;
        const int d4 = (i & 15) * 4;
        const float4 v = *(const float4*)&a.m0[((size_t)b * NN + n) * DD + d4];
        f16* msgs = (f16*)(g_ws + OFF_MSGS);
        *(f16x4*)&msgs[4u * i] = cvt4(v);
        return;
    }
    i -= N_MSG4;
    if (i < N_W16) {     // weight swizzle
        int ii = (int)i;
#pragma unroll
        for (int s = 0; s < 6; ++s) {
            const int sz = a.l[s].sz;
            if (ii < sz) {
                const int KB  = a.l[s].KB;
                const int ct  = ii / (KB * 512);
                const int r   = ii - ct * KB * 512;
                const int kb  = r >> 9;
                const int r2  = r & 511;
                const int ln  = r2 >> 3;
                const int j   = r2 & 7;
                const int k   = a.l[s].perm[kb] * 32 + (ln >> 4) * 8 + j;
                const int n   = ct * 16 + (ln & 15);
                const float v = (n < a.l[s].Nsrc) ? a.l[s].W[k * a.l[s].Nsrc + n] : 0.f;
                g_wf16[a.l[s].dst + ii] = (f16)v;
                return;
            }
            ii -= sz;
        }
        return;
    }
    i -= N_W16;
    if (i < N_HB4) {     // hebb f32 -> f16 (layout preserved)
        const unsigned e = i * 4u;
        const float4 v = *(const float4*)&a.hebbf[e];
        f16* hb = (f16*)(g_ws + OFF_HEBB16);
        *(f16x4*)&hb[e] = cvt4(v);
    }
}

// ---------------- MFMA layer1 (N=256, silu): 8 waves x (2 col-tiles, 4 m-tiles) ----
// R2/R3 proven map: each B-frag loaded exactly ONCE per block; A reused per c.
template<int KB, int KO>
__device__ __forceinline__ void mfma_layer1(const f16 (&Xs)[ROWS][XSTR], f16 (&Hs)[ROWS][XSTR],
                                            const f16* __restrict__ wp,
                                            const float* __restrict__ bias, int tid) {
    const int wv = tid >> 6, lane = tid & 63, lrow = lane & 15, quad = lane >> 4;
    __builtin_amdgcn_s_setprio(1);
#pragma unroll
    for (int c = 0; c < 2; ++c) {
        f32x4 acc[4];
#pragma unroll
        for (int m = 0; m < 4; ++m) acc[m] = (f32x4){0.f, 0.f, 0.f, 0.f};
#pragma unroll
        for (int kb = 0; kb < KB; ++kb) {
            const f16x8 bf = *(const f16x8*)&wp[(((wv * 2 + c) * KB + kb) * 64 + lane) * 8];
#pragma unroll
            for (int m = 0; m < 4; ++m) {
                const f16x8 a = *(const f16x8*)&Xs[m * 16 + lrow][(KO + kb) * 32 + quad * 8];
                acc[m] = __builtin_amdgcn_mfma_f32_16x16x32_f16(a, bf, acc[m], 0, 0, 0);
            }
        }
        const int col = (wv * 2 + c) * 16 + lrow;
        const float bb = bias[col];
#pragma unroll
        for (int m = 0; m < 4; ++m)
#pragma unroll
            for (int reg = 0; reg < 4; ++reg)
                Hs[m * 16 + quad * 4 + reg][col] = (f16)fast_silu(acc[m][reg] + bb);
    }
    __builtin_amdgcn_s_setprio(0);
}

// layer2 pair: wave handles col-tile `colt` (16 cols), m-tile half `mh` (32 rows)
__device__ __forceinline__ void layer2_pair(const f16 (&Hs)[ROWS][XSTR],
                                            const f16* __restrict__ wp2,
                                            int lane, int lrow, int quad, int colt, int mh,
                                            f32x4& t0, f32x4& t1) {
    __builtin_amdgcn_s_setprio(1);
#pragma unroll
    for (int kb = 0; kb < 8; ++kb) {
        const f16x8 a0 = *(const f16x8*)&Hs[mh * 32 + lrow][kb * 32 + quad * 8];
        const f16x8 a1 = *(const f16x8*)&Hs[mh * 32 + 16 + lrow][kb * 32 + quad * 8];
        const f16x8 b0 = *(const f16x8*)&wp2[((colt * 8 + kb) * 64 + lane) * 8];
        t0 = __builtin_amdgcn_mfma_f32_16x16x32_f16(a0, b0, t0, 0, 0, 0);
        t1 = __builtin_amdgcn_mfma_f32_16x16x32_f16(a1, b0, t1, 0, 0, 0);
    }
    __builtin_amdgcn_s_setprio(0);
}

// ---------------- per-step kernel (8 ordinary launches; L2 persists across them) ----
// Xs cols: 0..31 hebb | 32..95 h | 96..127 ident/ide2 | 128..191 recv/h_new | 192..255 inject
__global__ __launch_bounds__(512, 4) void step_kernel(
    const int* __restrict__ conn,
    const float* __restrict__ db1f, const float* __restrict__ db2f,
    const float* __restrict__ sb1f, const float* __restrict__ sb2f,
    const float* __restrict__ mb1f, const float* __restrict__ mb2f,
    const float* __restrict__ ccf, float* __restrict__ out, int step)
{
    float* h      = g_ws + OFF_H;
    float* wconn  = g_ws + OFF_WCONN;
    float* identG = g_ws + OFF_IDENT;
    f16*   msgsA  = (f16*)(g_ws + OFF_MSGS);
    const f16* hebb16 = (const f16*)(g_ws + OFF_HEBB16);

    __shared__ f16   Xs[ROWS][XSTR];      // 33792 B
    __shared__ f16   Hs[ROWS][XSTR];      // 33792 B
    __shared__ float wsigS[ROWS][36];     // 9216 B
    __shared__ float decayS[ROWS];        // 256 B   => 77056 B total (2 blocks/CU)

    const int tid   = threadIdx.x;
    const int n0    = blockIdx.x * TN;
    const int slice = n0 >> 9;
    const int lane  = tid & 63, wv = tid >> 6, lrow = lane & 15, quad = lane >> 4;
    const int colt  = wv & 3, mh = wv >> 2;     // layer2 mapping (R3 proven)

    // ---- per-wave conn rows (2 nodes/wave; lane l -> (node l>>5, k=l&31)) ----
    const int vconn = conn[(size_t)(n0 + wv * 2 + (lane >> 5)) * KK + (lane & 31)];

    // ---- staging (no block barrier needed before gather: wsig rows are same-wave) ----
    {   // wconn (sigmoid) + hebbian(f16): thread -> (row = tid>>3, k-group)
        const int r = tid >> 3, kg = (tid & 7) * 4;
        const int i = r >> 2, b = r & 3;
        const size_t g = (size_t)(b * NN + n0 + i) * KK + kg;
        const float4 w4 = *(const float4*)&wconn[g];
        const f16x4  hb = *(const f16x4*)&hebb16[g];
        float4 s4; s4.x = fast_sigmoid(w4.x); s4.y = fast_sigmoid(w4.y);
                   s4.z = fast_sigmoid(w4.z); s4.w = fast_sigmoid(w4.w);
        *(float4*)&wsigS[r][kg] = s4;
        *(f16x4*)&Xs[r][kg]     = hb;
    }
    if (tid < 128) {           // ident -> broadcast to 4 batch rows
        const int i = tid >> 3, jg = (tid & 7) * 4;
        const float4 iv = *(const float4*)&identG[(size_t)(n0 + i) * DID + jg];
        const f16x4 c = cvt4(iv);
#pragma unroll
        for (int b = 0; b < 4; ++b) *(f16x4*)&Xs[i * 4 + b][96 + jg] = c;
    }
#pragma unroll
    for (int ii = tid; ii < ROWS * 16; ii += 512) {   // h + inject
        const int r = ii >> 4, dg = (ii & 15) * 4;
        const int i = r >> 2, b = r & 3;
        const float4 hv = *(const float4*)&h[(size_t)(b * NN + n0 + i) * DD + dg];
        const float4 cv = *(const float4*)&ccf[(size_t)(b * TT + step) * DSCAN + slice * DD + dg];
        *(f16x4*)&Xs[r][32 + dg]  = cvt4(hv);
        *(f16x4*)&Xs[r][192 + dg] = cvt4(cv);
    }

    // ---- gather: recv[i,b,:] = sum_k wsig[i,b,k] * msgs[idx[i][k]][b][:] ----
    // wsigS rows 8wv..8wv+7 were written by THIS wave above (per-wave DS order).
    // v_fma_mix_f32: f16 source x f32 weight + f32 acc in ONE instruction
    // (bit-identical to cvt+fmaf: exact f16->f32 promote, then fma).
    {
        const int gb = (lane >> 4) & 3, c4 = (lane & 15) * 4;
        const f16* msgs_r = msgsA + (step & 1) * MSG_ELEMS;
#pragma unroll
        for (int ii = 0; ii < 2; ++ii) {
            const int i = wv * 2 + ii;
            float a0 = 0.f, a1 = 0.f, a2 = 0.f, a3 = 0.f;
#pragma unroll
            for (int k = 0; k < KK; ++k) {
                const int ix  = __builtin_amdgcn_readlane(vconn, ii * 32 + k);
                const float w = wsigS[i * 4 + gb][k];
                const uint2 m2 = *(const uint2*)&msgs_r[(size_t)ix * (BS * DD) + gb * DD + c4];
                asm("v_fma_mix_f32 %0, %4, %5, %0 op_sel:[0,0,0] op_sel_hi:[1,0,0]\n\t"
                    "v_fma_mix_f32 %1, %4, %5, %1 op_sel:[1,0,0] op_sel_hi:[1,0,0]\n\t"
                    "v_fma_mix_f32 %2, %6, %5, %2 op_sel:[0,0,0] op_sel_hi:[1,0,0]\n\t"
                    "v_fma_mix_f32 %3, %6, %5, %3 op_sel:[1,0,0] op_sel_hi:[1,0,0]"
                    : "+v"(a0), "+v"(a1), "+v"(a2), "+v"(a3)
                    : "v"(m2.x), "v"(w), "v"(m2.y));
            }
            f16x4 o4; o4[0] = (f16)a0; o4[1] = (f16)a1; o4[2] = (f16)a2; o4[3] = (f16)a3;
            *(f16x4*)&Xs[i * 4 + gb][128 + c4] = o4;
        }
    }

    // ---- ident RMW prefetch (consumed in mod-l2 epilogue, 2 phases later) ----
    const int obL = colt * 16 + lrow;
    float iold[2] = {0.f, 0.f}, i31old = 0.f;
    if (obL >= 33) {
        const int j = obL - 33;
        iold[0] = identG[(size_t)(n0 + (mh * 2 + 0) * 4 + quad) * DID + j];
        iold[1] = identG[(size_t)(n0 + (mh * 2 + 1) * 4 + quad) * DID + j];
    }
    if (colt < 2 && lrow == 0)
        i31old = identG[(size_t)(n0 + (mh * 2 + colt) * 4 + quad) * DID + 31];

    __syncthreads();

    mfma_layer1<8, 0>(Xs, Hs, g_wf16 + OFF16_DW1, db1f, tid);
    __syncthreads();

    // ---- mod layer2 (N=80): wconn' | decay | ident delta (+batch mean) ----
    {
        const f16* wp2 = g_wf16 + OFF16_DW2;
        f32x4 t0v = {0.f,0.f,0.f,0.f}, t1v = t0v, t2v = t0v;
        if (colt < 2) {
            __builtin_amdgcn_s_setprio(1);
#pragma unroll
            for (int kb = 0; kb < 8; ++kb) {
                const f16x8 a0 = *(const f16x8*)&Hs[mh * 32 + lrow][kb * 32 + quad * 8];
                const f16x8 a1 = *(const f16x8*)&Hs[mh * 32 + 16 + lrow][kb * 32 + quad * 8];
                const f16x8 b0 = *(const f16x8*)&wp2[((colt * 8 + kb) * 64 + lane) * 8];
                const f16x8 b4 = *(const f16x8*)&wp2[((32 + kb) * 64 + lane) * 8];
                t0v = __builtin_amdgcn_mfma_f32_16x16x32_f16(a0, b0, t0v, 0, 0, 0);
                t1v = __builtin_amdgcn_mfma_f32_16x16x32_f16(a1, b0, t1v, 0, 0, 0);
                const f16x8 am = (colt == 0) ? a0 : a1;
                t2v = __builtin_amdgcn_mfma_f32_16x16x32_f16(am, b4, t2v, 0, 0, 0);
            }
            __builtin_amdgcn_s_setprio(0);
        } else {
            layer2_pair(Hs, wp2, lane, lrow, quad, colt, mh, t0v, t1v);
        }
        const int ob = obL;
        if (ob < 32) {
            const float bb = db2f[ob];
#pragma unroll
            for (int mt = 0; mt < 2; ++mt) {
                const f32x4 tv = mt ? t1v : t0v;
                const int i = (mh * 2 + mt) * 4 + quad;
#pragma unroll
                for (int b = 0; b < 4; ++b)
                    wconn[((size_t)(b * NN + n0 + i)) * KK + ob] = tv[b] + bb;
            }
        } else if (ob == 32) {
            const float bb = db2f[32];
#pragma unroll
            for (int mt = 0; mt < 2; ++mt) {
                const f32x4 tv = mt ? t1v : t0v;
                const int i = (mh * 2 + mt) * 4 + quad;
#pragma unroll
                for (int b = 0; b < 4; ++b)
                    decayS[i * 4 + b] = fast_sigmoid(tv[b] + bb);
            }
        } else {
            const int j = ob - 33;
            const float bb = db2f[ob];
#pragma unroll
            for (int mt = 0; mt < 2; ++mt) {
                const f32x4 tv = mt ? t1v : t0v;
                const int i = (mh * 2 + mt) * 4 + quad;
                const float m = 0.25f * (tv[0] + tv[1] + tv[2] + tv[3]) + bb;
                const float v = iold[mt] + m;
                identG[(size_t)(n0 + i) * DID + j] = v;
                const f16 vh = (f16)v;
#pragma unroll
                for (int b = 0; b < 4; ++b) Xs[i * 4 + b][96 + j] = vh;
            }
        }
        if (colt < 2 && lrow == 0) {   // col 64 -> ident delta j=31
            const int i = (mh * 2 + colt) * 4 + quad;
            const float m = 0.25f * (t2v[0] + t2v[1] + t2v[2] + t2v[3]) + db2f[64];
            const float v = i31old + m;
            identG[(size_t)(n0 + i) * DID + 31] = v;
            const f16 vh = (f16)v;
#pragma unroll
            for (int b = 0; b < 4; ++b) Xs[i * 4 + b][96 + 31] = vh;
        }
    }
    __syncthreads();

    // ---- h prefetch (consumed in state-l2 epilogue, next phase) ----
    float hold[2][4];
#pragma unroll
    for (int mt = 0; mt < 2; ++mt)
#pragma unroll
        for (int b = 0; b < 4; ++b)
            hold[mt][b] = h[(size_t)(b * NN + n0 + (mh * 2 + mt) * 4 + quad) * DD + obL];

    // ---- state MLP: X cols 32..255 (weights K-permuted at init) ----
    mfma_layer1<7, 1>(Xs, Hs, g_wf16 + OFF16_SW1, sb1f, tid);
    __syncthreads();
    {
        f32x4 t0v = {0.f,0.f,0.f,0.f}, t1v = t0v;
        layer2_pair(Hs, g_wf16 + OFF16_SW2, lane, lrow, quad, colt, mh, t0v, t1v);
        const int o = obL;
        const float bb = sb2f[o];
#pragma unroll
        for (int mt = 0; mt < 2; ++mt) {
            const f32x4 tv = mt ? t1v : t0v;
            const int i = (mh * 2 + mt) * 4 + quad;
#pragma unroll
            for (int b = 0; b < 4; ++b) {
                const int r = i * 4 + b;
                const float hw = fast_tanh(tv[b] + bb);
                const float dc = decayS[r];
                const float hn = fmaf(dc, hold[mt][b], (1.f - dc) * hw);
                h[(size_t)(b * NN + n0 + i) * DD + o] = hn;
                out[((size_t)(b * TT + step) * NN + n0 + i) * DD + o] = hn;
                Xs[r][128 + o] = (f16)hn;   // msg input cols 128..191
            }
        }
    }
    __syncthreads();

    // ---- msg MLP: X cols 96..191 (ide2 | h_new), weights K-permuted ----
    mfma_layer1<3, 3>(Xs, Hs, g_wf16 + OFF16_MW1, mb1f, tid);
    __syncthreads();
    {
        f16* msgs_w = msgsA + ((step + 1) & 1) * MSG_ELEMS;
        f32x4 t0v = {0.f,0.f,0.f,0.f}, t1v = t0v;
        layer2_pair(Hs, g_wf16 + OFF16_MW2, lane, lrow, quad, colt, mh, t0v, t1v);
        const int o = obL;
        const float bb = mb2f[o];
#pragma unroll
        for (int mt = 0; mt < 2; ++mt) {
            const f32x4 tv = mt ? t1v : t0v;
            const int i = (mh * 2 + mt) * 4 + quad;
#pragma unroll
            for (int b = 0; b < 4; ++b)
                msgs_w[(size_t)(n0 + i) * (BS * DD) + b * DD + o] = (f16)fast_tanh(tv[b] + bb);
        }
    }
}

// ---------------- launch ----------------
extern "C" void kernel_launch(void* const* d_in, const int* in_sizes, int n_in,
                              void* d_out, int out_size, void* d_ws, size_t ws_size,
                              hipStream_t stream)
{
    (void)in_sizes; (void)n_in; (void)out_size; (void)d_ws; (void)ws_size;

    const float* cc   = (const float*)d_in[0];
    const float* h0   = (const float*)d_in[1];
    const float* m0   = (const float*)d_in[2];
    const float* w0   = (const float*)d_in[3];
    const float* hebb = (const float*)d_in[4];
    const float* idn  = (const float*)d_in[5];
    const float* sw1  = (const float*)d_in[6];
    const float* sb1  = (const float*)d_in[7];
    const float* sw2  = (const float*)d_in[8];
    const float* sb2  = (const float*)d_in[9];
    const float* mw1  = (const float*)d_in[10];
    const float* mb1  = (const float*)d_in[11];
    const float* mw2  = (const float*)d_in[12];
    const float* mb2  = (const float*)d_in[13];
    const float* dw1  = (const float*)d_in[14];
    const float* db1  = (const float*)d_in[15];
    const float* dw2  = (const float*)d_in[16];
    const float* db2  = (const float*)d_in[17];
    const int*   conn = (const int*)d_in[18];

    AllArgs aa;
    aa.seg[0] = { h0,  OFF_H,     (BS * NN * DD) / 4 };
    aa.seg[1] = { w0,  OFF_WCONN, (BS * NN * KK) / 4 };
    aa.seg[2] = { idn, OFF_IDENT, (NN * DID) / 4 };
    aa.m0 = m0;
    aa.l[0] = { dw1, 256, 8, OFF16_DW1, 16 * 8 * 512, {0,1,2,3,4,5,6,7} };
    aa.l[1] = { dw2,  65, 8, OFF16_DW2,  5 * 8 * 512, {0,1,2,3,4,5,6,7} };
    aa.l[2] = { sw1, 256, 7, OFF16_SW1, 16 * 7 * 512, {4,5,6,0,1,2,3,0} };
    aa.l[3] = { sw2,  64, 8, OFF16_SW2,  4 * 8 * 512, {0,1,2,3,4,5,6,7} };
    aa.l[4] = { mw1, 256, 3, OFF16_MW1, 16 * 3 * 512, {2,0,1,0,0,0,0,0} };
    aa.l[5] = { mw2,  64, 8, OFF16_MW2,  4 * 8 * 512, {0,1,2,3,4,5,6,7} };
    aa.hebbf = hebb;
    init_all<<<(N_INIT_TOTAL + 255) / 256, 256, 0, stream>>>(aa);

    float* outp = (float*)d_out;
    for (int t = 0; t < TT; ++t)
        step_kernel<<<NN / TN, 512, 0, stream>>>(conn, db1, db2, sb1, sb2,
                                                 mb1, mb2, cc, outp, t);
}

// Round 13
// 436.496 us; speedup vs baseline: 1.0606x; 1.0606x over previous
//
#include <hip/hip_runtime.h>

// ---------------- problem constants ----------------
#define NN    8192
#define KK    32
#define DD    64
#define DID   32
#define HD    256
#define BS    4
#define TT    8
#define DSCAN 1024
#define TN    16     // nodes per block
#define ROWS  64     // TN*BS MFMA rows; row r = i*4 + b
#define XSTR  264    // LDS row stride in f16

typedef _Float16 f16;
typedef f16   f16x4 __attribute__((ext_vector_type(4)));
typedef f16   f16x8 __attribute__((ext_vector_type(8)));
typedef float f32x4 __attribute__((ext_vector_type(4)));

// ---------------- device-global workspace (float units) ----------------
#define OFF_H      0u          // BS*NN*DD f32 = 2097152
#define OFF_WCONN  2097152u    // BS*NN*KK f32 = 1048576
#define OFF_IDENT  3145728u    // NN*DID f32 = 262144 (updated in place)
#define OFF_MSGS   3407872u    // two buffers: NN*BS*DD f16 = 1048576 float slots EACH -> [3407872, 5505024)
#define OFF_HEBB16 5505024u    // BS*NN*KK f16 = 524288 float slots
#define MSG_ELEMS  (NN * BS * DD)   // f16 elems per buffer (2097152)
#define WS_TOTAL   6029312u

__device__ float g_ws[WS_TOTAL];

// ---------------- pre-swizzled f16 weights (MFMA B-frag order, K-blocks permuted) ----
#define OFF16_DW1  0u        // 16*8*512
#define OFF16_DW2  65536u    // 5*8*512 (65 cols padded to 80)
#define OFF16_SW1  86016u    // 16*7*512
#define OFF16_SW2  143360u   // 4*8*512
#define OFF16_MW1  159744u   // 16*3*512
#define OFF16_MW2  184320u   // 4*8*512
#define W16_TOTAL  200704u

__device__ f16 g_wf16[W16_TOTAL];

// init work-item partition
#define N_COPY4  851968u     // (2097152+1048576+262144)/4
#define N_MSG4   524288u     // NN*BS*DD/4 (f16x4 groups)
#define N_W16    200704u
#define N_HB4    262144u     // BS*NN*KK/4 (f16x4 groups)
#define N_INIT_TOTAL (N_COPY4 + N_MSG4 + N_W16 + N_HB4)

// ---------------- numeric helpers ----------------
__device__ __forceinline__ float fast_sigmoid(float x) { return 1.f / (1.f + __expf(-x)); }
__device__ __forceinline__ float fast_silu(float x)    { return x / (1.f + __expf(-x)); }
__device__ __forceinline__ float fast_tanh(float x) {
    float ax = fabsf(x);
    float t  = __expf(-2.f * ax);
    float r  = (1.f - t) / (1.f + t);
    return copysignf(r, x);
}
__device__ __forceinline__ f16x4 cvt4(float4 v) {
    f16x4 o; o[0] = (f16)v.x; o[1] = (f16)v.y; o[2] = (f16)v.z; o[3] = (f16)v.w; return o;
}

// ---------------- merged init kernel ----------------
struct Seg { const float* src; unsigned int dst_off; unsigned int len4; };
struct WL { const float* W; int Nsrc; int KB; unsigned int dst; int sz; int perm[8]; };
struct AllArgs { Seg seg[3]; const float* m0; WL l[6]; const float* hebbf; };

__global__ void init_all(AllArgs a) {
    unsigned int i = blockIdx.x * 256 + threadIdx.x;
    if (i < N_COPY4) {
#pragma unroll
        for (int s = 0; s < 3; ++s) {
            unsigned int L = a.seg[s].len4;
            if (i < L) {
                const float4 v = ((const float4*)a.seg[s].src)[i];
                *(float4*)&g_ws[a.seg[s].dst_off + 4u * i] = v;
                return;
            }
            i -= L;
        }
        return;
    }
    i -= N_COPY4;
    if (i < N_MSG4) {    // msgs: [b][n][d] f32 -> [n][b][d] f16 (buffer 0)
        const int n  = i >> 6;
        const int b  = (i >> 4) & 3;
        const int d4 = (i & 15) * 4;
        const float4 v = *(const float4*)&a.m0[((size_t)b * NN + n) * DD + d4];
        f16* msgs = (f16*)(g_ws + OFF_MSGS);
        *(f16x4*)&msgs[4u * i] = cvt4(v);
        return;
    }
    i -= N_MSG4;
    if (i < N_W16) {     // weight swizzle
        int ii = (int)i;
#pragma unroll
        for (int s = 0; s < 6; ++s) {
            const int sz = a.l[s].sz;
            if (ii < sz) {
                const int KB  = a.l[s].KB;
                const int ct  = ii / (KB * 512);
                const int r   = ii - ct * KB * 512;
                const int kb  = r >> 9;
                const int r2  = r & 511;
                const int ln  = r2 >> 3;
                const int j   = r2 & 7;
                const int k   = a.l[s].perm[kb] * 32 + (ln >> 4) * 8 + j;
                const int n   = ct * 16 + (ln & 15);
                const float v = (n < a.l[s].Nsrc) ? a.l[s].W[k * a.l[s].Nsrc + n] : 0.f;
                g_wf16[a.l[s].dst + ii] = (f16)v;
                return;
            }
            ii -= sz;
        }
        return;
    }
    i -= N_W16;
    if (i < N_HB4) {     // hebb f32 -> f16 (layout preserved)
        const unsigned e = i * 4u;
        const float4 v = *(const float4*)&a.hebbf[e];
        f16* hb = (f16*)(g_ws + OFF_HEBB16);
        *(f16x4*)&hb[e] = cvt4(v);
    }
}

// ---------------- MFMA layer1 (N=256, silu): 8 waves x (2 col-tiles, 4 m-tiles) ----
// R2/R3 proven map: each B-frag loaded exactly ONCE per block; A reused per c.
template<int KB, int KO>
__device__ __forceinline__ void mfma_layer1(const f16 (&Xs)[ROWS][XSTR], f16 (&Hs)[ROWS][XSTR],
                                            const f16* __restrict__ wp,
                                            const float* __restrict__ bias, int tid) {
    const int wv = tid >> 6, lane = tid & 63, lrow = lane & 15, quad = lane >> 4;
#pragma unroll
    for (int c = 0; c < 2; ++c) {
        f32x4 acc[4];
#pragma unroll
        for (int m = 0; m < 4; ++m) acc[m] = (f32x4){0.f, 0.f, 0.f, 0.f};
#pragma unroll
        for (int kb = 0; kb < KB; ++kb) {
            const f16x8 bf = *(const f16x8*)&wp[(((wv * 2 + c) * KB + kb) * 64 + lane) * 8];
#pragma unroll
            for (int m = 0; m < 4; ++m) {
                const f16x8 a = *(const f16x8*)&Xs[m * 16 + lrow][(KO + kb) * 32 + quad * 8];
                acc[m] = __builtin_amdgcn_mfma_f32_16x16x32_f16(a, bf, acc[m], 0, 0, 0);
            }
        }
        const int col = (wv * 2 + c) * 16 + lrow;
        const float bb = bias[col];
#pragma unroll
        for (int m = 0; m < 4; ++m)
#pragma unroll
            for (int reg = 0; reg < 4; ++reg)
                Hs[m * 16 + quad * 4 + reg][col] = (f16)fast_silu(acc[m][reg] + bb);
    }
}

// layer2 pair: wave handles col-tile `colt` (16 cols), m-tile half `mh` (32 rows)
__device__ __forceinline__ void layer2_pair(const f16 (&Hs)[ROWS][XSTR],
                                            const f16* __restrict__ wp2,
                                            int lane, int lrow, int quad, int colt, int mh,
                                            f32x4& t0, f32x4& t1) {
#pragma unroll
    for (int kb = 0; kb < 8; ++kb) {
        const f16x8 a0 = *(const f16x8*)&Hs[mh * 32 + lrow][kb * 32 + quad * 8];
        const f16x8 a1 = *(const f16x8*)&Hs[mh * 32 + 16 + lrow][kb * 32 + quad * 8];
        const f16x8 b0 = *(const f16x8*)&wp2[((colt * 8 + kb) * 64 + lane) * 8];
        t0 = __builtin_amdgcn_mfma_f32_16x16x32_f16(a0, b0, t0, 0, 0, 0);
        t1 = __builtin_amdgcn_mfma_f32_16x16x32_f16(a1, b0, t1, 0, 0, 0);
    }
}

// ---------------- per-step kernel (8 ordinary launches; L2 persists across them) ----
// Xs cols: 0..31 hebb | 32..95 h | 96..127 ident/ide2 | 128..191 recv/h_new | 192..255 inject
__global__ __launch_bounds__(512, 4) void step_kernel(
    const int* __restrict__ conn,
    const float* __restrict__ db1f, const float* __restrict__ db2f,
    const float* __restrict__ sb1f, const float* __restrict__ sb2f,
    const float* __restrict__ mb1f, const float* __restrict__ mb2f,
    const float* __restrict__ ccf, float* __restrict__ out, int step)
{
    float* h      = g_ws + OFF_H;
    float* wconn  = g_ws + OFF_WCONN;
    float* identG = g_ws + OFF_IDENT;
    f16*   msgsA  = (f16*)(g_ws + OFF_MSGS);
    const f16* hebb16 = (const f16*)(g_ws + OFF_HEBB16);

    __shared__ f16   Xs[ROWS][XSTR];      // 33792 B
    __shared__ f16   Hs[ROWS][XSTR];      // 33792 B
    __shared__ float wsigS[ROWS][36];     // 9216 B
    __shared__ float decayS[ROWS];        // 256 B   => 77056 B total (2 blocks/CU)

    const int tid   = threadIdx.x;
    const int n0    = blockIdx.x * TN;
    const int slice = n0 >> 9;
    const int lane  = tid & 63, wv = tid >> 6, lrow = lane & 15, quad = lane >> 4;
    const int colt  = wv & 3, mh = wv >> 2;     // layer2 mapping (R3 proven)

    // ---- per-wave conn rows (2 nodes/wave; lane l -> (node l>>5, k=l&31)) ----
    const int vconn = conn[(size_t)(n0 + wv * 2 + (lane >> 5)) * KK + (lane & 31)];

    // ---- staging (no block barrier needed before gather: wsig rows are same-wave) ----
    {   // wconn (sigmoid) + hebbian(f16): thread -> (row = tid>>3, k-group)
        const int r = tid >> 3, kg = (tid & 7) * 4;
        const int i = r >> 2, b = r & 3;
        const size_t g = (size_t)(b * NN + n0 + i) * KK + kg;
        const float4 w4 = *(const float4*)&wconn[g];
        const f16x4  hb = *(const f16x4*)&hebb16[g];
        float4 s4; s4.x = fast_sigmoid(w4.x); s4.y = fast_sigmoid(w4.y);
                   s4.z = fast_sigmoid(w4.z); s4.w = fast_sigmoid(w4.w);
        *(float4*)&wsigS[r][kg] = s4;
        *(f16x4*)&Xs[r][kg]     = hb;
    }
    if (tid < 128) {           // ident -> broadcast to 4 batch rows
        const int i = tid >> 3, jg = (tid & 7) * 4;
        const float4 iv = *(const float4*)&identG[(size_t)(n0 + i) * DID + jg];
        const f16x4 c = cvt4(iv);
#pragma unroll
        for (int b = 0; b < 4; ++b) *(f16x4*)&Xs[i * 4 + b][96 + jg] = c;
    }
#pragma unroll
    for (int ii = tid; ii < ROWS * 16; ii += 512) {   // h + inject
        const int r = ii >> 4, dg = (ii & 15) * 4;
        const int i = r >> 2, b = r & 3;
        const float4 hv = *(const float4*)&h[(size_t)(b * NN + n0 + i) * DD + dg];
        const float4 cv = *(const float4*)&ccf[(size_t)(b * TT + step) * DSCAN + slice * DD + dg];
        *(f16x4*)&Xs[r][32 + dg]  = cvt4(hv);
        *(f16x4*)&Xs[r][192 + dg] = cvt4(cv);
    }

    // ---- gather: recv[i,b,:] = sum_k wsig[i,b,k] * msgs[idx[i][k]][b][:] ----
    // wsigS rows 8wv..8wv+7 were written by THIS wave above (per-wave DS order).
    {
        const int gb = (lane >> 4) & 3, c4 = (lane & 15) * 4;
        const f16* msgs_r = msgsA + (step & 1) * MSG_ELEMS;
#pragma unroll
        for (int ii = 0; ii < 2; ++ii) {
            const int i = wv * 2 + ii;
            f32x4 a = {0.f, 0.f, 0.f, 0.f};
#pragma unroll
            for (int k = 0; k < KK; ++k) {
                const int ix  = __builtin_amdgcn_readlane(vconn, ii * 32 + k);
                const float w = wsigS[i * 4 + gb][k];
                const f16x4 m = *(const f16x4*)&msgs_r[(size_t)ix * (BS * DD) + gb * DD + c4];
                a[0] = fmaf(w, (float)m[0], a[0]); a[1] = fmaf(w, (float)m[1], a[1]);
                a[2] = fmaf(w, (float)m[2], a[2]); a[3] = fmaf(w, (float)m[3], a[3]);
            }
            f16x4 o4; o4[0] = (f16)a[0]; o4[1] = (f16)a[1]; o4[2] = (f16)a[2]; o4[3] = (f16)a[3];
            *(f16x4*)&Xs[i * 4 + gb][128 + c4] = o4;
        }
    }

    // ---- ident RMW prefetch (consumed in mod-l2 epilogue, 2 phases later) ----
    const int obL = colt * 16 + lrow;
    float iold[2] = {0.f, 0.f}, i31old = 0.f;
    if (obL >= 33) {
        const int j = obL - 33;
        iold[0] = identG[(size_t)(n0 + (mh * 2 + 0) * 4 + quad) * DID + j];
        iold[1] = identG[(size_t)(n0 + (mh * 2 + 1) * 4 + quad) * DID + j];
    }
    if (colt < 2 && lrow == 0)
        i31old = identG[(size_t)(n0 + (mh * 2 + colt) * 4 + quad) * DID + 31];

    __syncthreads();

    mfma_layer1<8, 0>(Xs, Hs, g_wf16 + OFF16_DW1, db1f, tid);
    __syncthreads();

    // ---- mod layer2 (N=80): wconn' | decay | ident delta (+batch mean) ----
    {
        const f16* wp2 = g_wf16 + OFF16_DW2;
        f32x4 t0v = {0.f,0.f,0.f,0.f}, t1v = t0v, t2v = t0v;
        if (colt < 2) {
#pragma unroll
            for (int kb = 0; kb < 8; ++kb) {
                const f16x8 a0 = *(const f16x8*)&Hs[mh * 32 + lrow][kb * 32 + quad * 8];
                const f16x8 a1 = *(const f16x8*)&Hs[mh * 32 + 16 + lrow][kb * 32 + quad * 8];
                const f16x8 b0 = *(const f16x8*)&wp2[((colt * 8 + kb) * 64 + lane) * 8];
                const f16x8 b4 = *(const f16x8*)&wp2[((32 + kb) * 64 + lane) * 8];
                t0v = __builtin_amdgcn_mfma_f32_16x16x32_f16(a0, b0, t0v, 0, 0, 0);
                t1v = __builtin_amdgcn_mfma_f32_16x16x32_f16(a1, b0, t1v, 0, 0, 0);
                const f16x8 am = (colt == 0) ? a0 : a1;
                t2v = __builtin_amdgcn_mfma_f32_16x16x32_f16(am, b4, t2v, 0, 0, 0);
            }
        } else {
            layer2_pair(Hs, wp2, lane, lrow, quad, colt, mh, t0v, t1v);
        }
        const int ob = obL;
        if (ob < 32) {
            const float bb = db2f[ob];
#pragma unroll
            for (int mt = 0; mt < 2; ++mt) {
                const f32x4 tv = mt ? t1v : t0v;
                const int i = (mh * 2 + mt) * 4 + quad;
#pragma unroll
                for (int b = 0; b < 4; ++b)
                    wconn[((size_t)(b * NN + n0 + i)) * KK + ob] = tv[b] + bb;
            }
        } else if (ob == 32) {
            const float bb = db2f[32];
#pragma unroll
            for (int mt = 0; mt < 2; ++mt) {
                const f32x4 tv = mt ? t1v : t0v;
                const int i = (mh * 2 + mt) * 4 + quad;
#pragma unroll
                for (int b = 0; b < 4; ++b)
                    decayS[i * 4 + b] = fast_sigmoid(tv[b] + bb);
            }
        } else {
            const int j = ob - 33;
            const float bb = db2f[ob];
#pragma unroll
            for (int mt = 0; mt < 2; ++mt) {
                const f32x4 tv = mt ? t1v : t0v;
                const int i = (mh * 2 + mt) * 4 + quad;
                const float m = 0.25f * (tv[0] + tv[1] + tv[2] + tv[3]) + bb;
                const float v = iold[mt] + m;
                identG[(size_t)(n0 + i) * DID + j] = v;
                const f16 vh = (f16)v;
#pragma unroll
                for (int b = 0; b < 4; ++b) Xs[i * 4 + b][96 + j] = vh;
            }
        }
        if (colt < 2 && lrow == 0) {   // col 64 -> ident delta j=31
            const int i = (mh * 2 + colt) * 4 + quad;
            const float m = 0.25f * (t2v[0] + t2v[1] + t2v[2] + t2v[3]) + db2f[64];
            const float v = i31old + m;
            identG[(size_t)(n0 + i) * DID + 31] = v;
            const f16 vh = (f16)v;
#pragma unroll
            for (int b = 0; b < 4; ++b) Xs[i * 4 + b][96 + 31] = vh;
        }
    }
    __syncthreads();

    // ---- h prefetch (consumed in state-l2 epilogue, next phase) ----
    float hold[2][4];
#pragma unroll
    for (int mt = 0; mt < 2; ++mt)
#pragma unroll
        for (int b = 0; b < 4; ++b)
            hold[mt][b] = h[(size_t)(b * NN + n0 + (mh * 2 + mt) * 4 + quad) * DD + obL];

    // ---- state MLP: X cols 32..255 (weights K-permuted at init) ----
    mfma_layer1<7, 1>(Xs, Hs, g_wf16 + OFF16_SW1, sb1f, tid);
    __syncthreads();
    {
        f32x4 t0v = {0.f,0.f,0.f,0.f}, t1v = t0v;
        layer2_pair(Hs, g_wf16 + OFF16_SW2, lane, lrow, quad, colt, mh, t0v, t1v);
        const int o = obL;
        const float bb = sb2f[o];
#pragma unroll
        for (int mt = 0; mt < 2; ++mt) {
            const f32x4 tv = mt ? t1v : t0v;
            const int i = (mh * 2 + mt) * 4 + quad;
#pragma unroll
            for (int b = 0; b < 4; ++b) {
                const int r = i * 4 + b;
                const float hw = fast_tanh(tv[b] + bb);
                const float dc = decayS[r];
                const float hn = fmaf(dc, hold[mt][b], (1.f - dc) * hw);
                h[(size_t)(b * NN + n0 + i) * DD + o] = hn;
                out[((size_t)(b * TT + step) * NN + n0 + i) * DD + o] = hn;
                Xs[r][128 + o] = (f16)hn;   // msg input cols 128..191
            }
        }
    }
    __syncthreads();

    // ---- msg MLP: X cols 96..191 (ide2 | h_new), weights K-permuted ----
    mfma_layer1<3, 3>(Xs, Hs, g_wf16 + OFF16_MW1, mb1f, tid);
    __syncthreads();
    {
        f16* msgs_w = msgsA + ((step + 1) & 1) * MSG_ELEMS;
        f32x4 t0v = {0.f,0.f,0.f,0.f}, t1v = t0v;
        layer2_pair(Hs, g_wf16 + OFF16_MW2, lane, lrow, quad, colt, mh, t0v, t1v);
        const int o = obL;
        const float bb = mb2f[o];
#pragma unroll
        for (int mt = 0; mt < 2; ++mt) {
            const f32x4 tv = mt ? t1v : t0v;
            const int i = (mh * 2 + mt) * 4 + quad;
#pragma unroll
            for (int b = 0; b < 4; ++b)
                msgs_w[(size_t)(n0 + i) * (BS * DD) + b * DD + o] = (f16)fast_tanh(tv[b] + bb);
        }
    }
}

// ---------------- launch ----------------
extern "C" void kernel_launch(void* const* d_in, const int* in_sizes, int n_in,
                              void* d_out, int out_size, void* d_ws, size_t ws_size,
                              hipStream_t stream)
{
    (void)in_sizes; (void)n_in; (void)out_size; (void)d_ws; (void)ws_size;

    const float* cc   = (const float*)d_in[0];
    const float* h0   = (const float*)d_in[1];
    const float* m0   = (const float*)d_in[2];
    const float* w0   = (const float*)d_in[3];
    const float* hebb = (const float*)d_in[4];
    const float* idn  = (const float*)d_in[5];
    const float* sw1  = (const float*)d_in[6];
    const float* sb1  = (const float*)d_in[7];
    const float* sw2  = (const float*)d_in[8];
    const float* sb2  = (const float*)d_in[9];
    const float* mw1  = (const float*)d_in[10];
    const float* mb1  = (const float*)d_in[11];
    const float* mw2  = (const float*)d_in[12];
    const float* mb2  = (const float*)d_in[13];
    const float* dw1  = (const float*)d_in[14];
    const float* db1  = (const float*)d_in[15];
    const float* dw2  = (const float*)d_in[16];
    const float* db2  = (const float*)d_in[17];
    const int*   conn = (const int*)d_in[18];

    AllArgs aa;
    aa.seg[0] = { h0,  OFF_H,     (BS * NN * DD) / 4 };
    aa.seg[1] = { w0,  OFF_WCONN, (BS * NN * KK) / 4 };
    aa.seg[2] = { idn, OFF_IDENT, (NN * DID) / 4 };
    aa.m0 = m0;
    aa.l[0] = { dw1, 256, 8, OFF16_DW1, 16 * 8 * 512, {0,1,2,3,4,5,6,7} };
    aa.l[1] = { dw2,  65, 8, OFF16_DW2,  5 * 8 * 512, {0,1,2,3,4,5,6,7} };
    aa.l[2] = { sw1, 256, 7, OFF16_SW1, 16 * 7 * 512, {4,5,6,0,1,2,3,0} };
    aa.l[3] = { sw2,  64, 8, OFF16_SW2,  4 * 8 * 512, {0,1,2,3,4,5,6,7} };
    aa.l[4] = { mw1, 256, 3, OFF16_MW1, 16 * 3 * 512, {2,0,1,0,0,0,0,0} };
    aa.l[5] = { mw2,  64, 8, OFF16_MW2,  4 * 8 * 512, {0,1,2,3,4,5,6,7} };
    aa.hebbf = hebb;
    init_all<<<(N_INIT_TOTAL + 255) / 256, 256, 0, stream>>>(aa);

    float* outp = (float*)d_out;
    for (int t = 0; t < TT; ++t)
        step_kernel<<<NN / TN, 512, 0, stream>>>(conn, db1, db2, sb1, sb2,
                                                 mb1, mb2, cc, outp, t);
}